// Round 3
// baseline (539.083 us; speedup 1.0000x reference)
//
#include <hip/hip_runtime.h>
#include <stdint.h>

// Self-attention, SEQ=8192, D=768, single head.
//   K0a: x fp32->bf16 (float4 vectorized)
//   K0b: Wq/Wk/Wv fp32->bf16 (one launch, blockIdx.z selects)
//   K1a: Q=(x Wq^T)/sqrt(768) and K=x Wk^T fused via blockIdx.z (MODE 0)
//   K1b: Vt = Wv x^T (MODE 0)
//   K2 : P' = exp(Q K^T) bf16 + atomic row sums (MODE 1)
//   K3 : out += (P'_chunk V)/rowsum, split-K x4, fp32 atomicAdd (MODE 2)
// Round-2 profile: K3 was 225us @ 16% occupancy (384 blocks) -> split-K.

#define SEQ    8192
#define DMODEL 768
#define KSPLIT 4

typedef short bf16x8 __attribute__((ext_vector_type(8)));
typedef float f32x4  __attribute__((ext_vector_type(4)));

__device__ __forceinline__ unsigned short f2bf(float f) {
  union { float f; unsigned int u; } v; v.f = f;
  unsigned int u = v.u;
  u += 0x7FFFu + ((u >> 16) & 1u);   // round-to-nearest-even
  return (unsigned short)(u >> 16);
}

__device__ __forceinline__ void async16(void* lds, const void* g) {
  __builtin_amdgcn_global_load_lds((const __attribute__((address_space(1))) void*)g,
                                   (__attribute__((address_space(3))) void*)lds,
                                   16, 0, 0);
}

// x convert: float4 -> 4x bf16, n % 1024 == 0
__global__ void convert_x(const float* __restrict__ src,
                          unsigned short* __restrict__ dst, int n4) {
  int i = blockIdx.x * blockDim.x + threadIdx.x;
  if (i >= n4) return;
  const float4 f = ((const float4*)src)[i];
  ushort4 o;
  o.x = f2bf(f.x); o.y = f2bf(f.y); o.z = f2bf(f.z); o.w = f2bf(f.w);
  ((ushort4*)dst)[i] = o;
}

// three same-size weight converts in one launch; blockIdx.z selects
__global__ void convert_w(const float* __restrict__ s0, const float* __restrict__ s1,
                          const float* __restrict__ s2,
                          unsigned short* __restrict__ d0, unsigned short* __restrict__ d1,
                          unsigned short* __restrict__ d2, int n4) {
  const float* s = (blockIdx.z == 0) ? s0 : (blockIdx.z == 1) ? s1 : s2;
  unsigned short* d = (blockIdx.z == 0) ? d0 : (blockIdx.z == 1) ? d1 : d2;
  int i = blockIdx.x * blockDim.x + threadIdx.x;
  if (i >= n4) return;
  const float4 f = ((const float4*)s)[i];
  ushort4 o;
  o.x = f2bf(f.x); o.y = f2bf(f.y); o.z = f2bf(f.z); o.w = f2bf(f.w);
  ((ushort4*)d)[i] = o;
}

// C[m,n] = sum_k A[m,k]*B[n,k]  (A:[M,K], B:[N,K] bf16 row-major)
// MODE 0: store bf16 C*alpha.  gridDim.z==2 => z=1 uses B2/Cout2/alpha2 (QK fusion)
// MODE 1: store bf16 exp(C), atomicAdd per-row exp-sums into rowsum
// MODE 2: split-K over gridDim.z (kChunk each); atomicAdd fp32 C/rowsum[m] into Cout
template <int MODE>
__launch_bounds__(256)
__global__ void gemm_bt(const unsigned short* __restrict__ A,
                        const unsigned short* __restrict__ B,
                        void* __restrict__ Cout,
                        int M, int N, int K, float alpha,
                        float* __restrict__ rowsum, int kChunk,
                        const unsigned short* __restrict__ B2,
                        void* __restrict__ Cout2, float alpha2) {
  __shared__ __align__(16) unsigned short lA[128 * 32];
  __shared__ __align__(16) unsigned short lB[128 * 32];

  if (MODE == 0) {
    if (blockIdx.z == 1) { B = B2; Cout = Cout2; alpha = alpha2; }
  }
  const int kOff = (MODE == 2) ? blockIdx.z * kChunk : 0;

  const int t    = threadIdx.x;
  const int w    = t >> 6;
  const int l    = t & 63;
  const int quad = l >> 4;
  const int lr   = l & 15;
  const int m0   = blockIdx.y * 128;
  const int n0   = blockIdx.x * 128;
  const int wm   = (w & 1) * 64;
  const int wn   = (w >> 1) * 64;

  f32x4 acc[4][4] = {};

  const int nk = kChunk >> 5;
  for (int kt = 0; kt < nk; ++kt) {
    const int k0 = kOff + (kt << 5);
    __syncthreads();
    // Stage A,B tiles: 512 x 16B chunks each; thread t takes chunks t, t+256.
    // LDS row-major [128][32] bf16; chunk c -> (row=c>>2, k=(c&3)*8);
    // lds byte offset c*16 = wave_base + lane*16 (global_load_lds constraint).
#pragma unroll
    for (int h = 0; h < 2; ++h) {
      int c   = t + (h << 8);
      int row = c >> 2;
      int kc  = (c & 3) << 3;
      async16(&lA[c << 3], A + (size_t)(m0 + row) * K + (k0 + kc));
      async16(&lB[c << 3], B + (size_t)(n0 + row) * K + (k0 + kc));
    }
    __syncthreads();

    bf16x8 af[4], bfr[4];
#pragma unroll
    for (int i = 0; i < 4; ++i) {
      af[i]  = *(const bf16x8*)&lA[(wm + i * 16 + lr) * 32 + quad * 8];
      bfr[i] = *(const bf16x8*)&lB[(wn + i * 16 + lr) * 32 + quad * 8];
    }
#pragma unroll
    for (int mi = 0; mi < 4; ++mi)
#pragma unroll
      for (int ni = 0; ni < 4; ++ni)
        acc[mi][ni] = __builtin_amdgcn_mfma_f32_16x16x32_bf16(af[mi], bfr[ni],
                                                              acc[mi][ni], 0, 0, 0);
  }

  // C/D layout (verified m89): col = lane&15, row = quad*4 + reg
  if (MODE == 0) {
    unsigned short* C = (unsigned short*)Cout;
#pragma unroll
    for (int mi = 0; mi < 4; ++mi)
#pragma unroll
      for (int r = 0; r < 4; ++r) {
        int m = m0 + wm + mi * 16 + quad * 4 + r;
#pragma unroll
        for (int ni = 0; ni < 4; ++ni) {
          int n = n0 + wn + ni * 16 + lr;
          C[(size_t)m * N + n] = f2bf(acc[mi][ni][r] * alpha);
        }
      }
  } else if (MODE == 1) {
    unsigned short* C = (unsigned short*)Cout;
#pragma unroll
    for (int mi = 0; mi < 4; ++mi)
#pragma unroll
      for (int r = 0; r < 4; ++r) {
        int m = m0 + wm + mi * 16 + quad * 4 + r;
        float s = 0.f;
#pragma unroll
        for (int ni = 0; ni < 4; ++ni) {
          int n = n0 + wn + ni * 16 + lr;
          float p = __expf(acc[mi][ni][r]);
          C[(size_t)m * N + n] = f2bf(p);
          s += p;
        }
#pragma unroll
        for (int off = 1; off < 16; off <<= 1) s += __shfl_xor(s, off, 64);
        if (lr == 0) atomicAdd(&rowsum[m], s);
      }
  } else {
    float* C = (float*)Cout;   // d_out fp32, zero-initialized; split-K partials
#pragma unroll
    for (int mi = 0; mi < 4; ++mi)
#pragma unroll
      for (int r = 0; r < 4; ++r) {
        int m = m0 + wm + mi * 16 + quad * 4 + r;
        float inv = 1.0f / rowsum[m];
#pragma unroll
        for (int ni = 0; ni < 4; ++ni) {
          int n = n0 + wn + ni * 16 + lr;
          atomicAdd(&C[(size_t)m * N + n], acc[mi][ni][r] * inv);
        }
      }
  }
}

extern "C" void kernel_launch(void* const* d_in, const int* in_sizes, int n_in,
                              void* d_out, int out_size, void* d_ws, size_t ws_size,
                              hipStream_t stream) {
  const float* x  = (const float*)d_in[0];
  const float* Wq = (const float*)d_in[1];
  const float* Wk = (const float*)d_in[2];
  const float* Wv = (const float*)d_in[3];

  char* ws = (char*)d_ws;
  unsigned short* xb     = (unsigned short*)(ws + 0);
  unsigned short* Qb     = (unsigned short*)(ws + 12582912);
  unsigned short* Kb     = (unsigned short*)(ws + 25165824);
  unsigned short* Vtb    = (unsigned short*)(ws + 37748736);
  unsigned short* wqb    = (unsigned short*)(ws + 50331648);
  unsigned short* wkb    = (unsigned short*)(ws + 51511296);
  unsigned short* wvb    = (unsigned short*)(ws + 52690944);
  float*          rowsum = (float*)(ws + 53870592);
  unsigned short* Pb     = (unsigned short*)(ws + 53903360);
  const size_t need = 53903360u + (size_t)SEQ * SEQ * 2u;
  if (ws_size < need) return;

  hipMemsetAsync(rowsum, 0, SEQ * sizeof(float), stream);
  hipMemsetAsync(d_out, 0, (size_t)out_size * sizeof(float), stream);

  convert_x<<<SEQ * DMODEL / 1024, 256, 0, stream>>>(x, xb, SEQ * DMODEL / 4);
  convert_w<<<dim3(DMODEL * DMODEL / 1024, 1, 3), 256, 0, stream>>>(
      Wq, Wk, Wv, wqb, wkb, wvb, DMODEL * DMODEL / 4);

  const float alpha_q = 0.03608439182435161f;  // 1/sqrt(768)
  dim3 blk(256);
  // Q=(x Wq^T)*alpha and K=x Wk^T fused (z selects)   [8192,768] each
  gemm_bt<0><<<dim3(DMODEL / 128, SEQ / 128, 2), blk, 0, stream>>>(
      xb, wqb, Qb, SEQ, DMODEL, DMODEL, alpha_q, nullptr, DMODEL,
      wkb, Kb, 1.0f);
  // Vt = Wv x^T   [768,8192]
  gemm_bt<0><<<dim3(SEQ / 128, DMODEL / 128, 1), blk, 0, stream>>>(
      wvb, xb, Vtb, DMODEL, SEQ, DMODEL, 1.0f, nullptr, DMODEL,
      nullptr, nullptr, 1.0f);
  // P' = exp(Q K^T) + rowsums   [8192,8192] bf16
  gemm_bt<1><<<dim3(SEQ / 128, SEQ / 128, 1), blk, 0, stream>>>(
      Qb, Kb, Pb, SEQ, SEQ, DMODEL, 1.0f, rowsum, DMODEL,
      nullptr, nullptr, 1.0f);
  // out += (P'_chunk V)/rowsum, split-K x4 -> fp32 d_out
  gemm_bt<2><<<dim3(DMODEL / 128, SEQ / 128, KSPLIT), blk, 0, stream>>>(
      Pb, Vtb, d_out, SEQ, DMODEL, SEQ, 1.0f, rowsum, SEQ / KSPLIT,
      nullptr, nullptr, 1.0f);
}

// Round 4
// 471.235 us; speedup vs baseline: 1.1440x; 1.1440x over previous
//
#include <hip/hip_runtime.h>
#include <stdint.h>

// Self-attention, SEQ=8192, D=768, single head.
//   K0a: x fp32->bf16 (float4 vectorized)
//   K0b: Wq/Wk/Wv fp32->bf16 (one launch, blockIdx.z selects)
//   K1a: Q=(x Wq^T)/sqrt(768) and K=x Wk^T fused via blockIdx.z (MODE 0)
//   K1b: Vt = Wv x^T (MODE 0)
//   K2 : P' = exp(Q K^T) bf16 + atomic row sums (MODE 1)
//   K3 : out += (P'_chunk V)/rowsum, split-K x4, fp32 atomicAdd (MODE 2)
// Round-3 finding: K3 pinned at 225us regardless of occupancy/BW; per-CU
// K-iter cost 586ns vs m97's 294ns => staging-latency-bound. Cause: x-fastest
// grids put same-A-panel blocks on DIFFERENT XCDs (id%8 round-robin), so
// shared panels are HBM-latency every time (FETCH 630MB vs 171MB unique).
// Round-4 change: blockIdx.x = M-tile, blockIdx.y = N-tile => same-A blocks
// are 64 ids apart (== same XCD), A-panels become L2-resident.

#define SEQ    8192
#define DMODEL 768
#define KSPLIT 4

typedef short bf16x8 __attribute__((ext_vector_type(8)));
typedef float f32x4  __attribute__((ext_vector_type(4)));

__device__ __forceinline__ unsigned short f2bf(float f) {
  union { float f; unsigned int u; } v; v.f = f;
  unsigned int u = v.u;
  u += 0x7FFFu + ((u >> 16) & 1u);   // round-to-nearest-even
  return (unsigned short)(u >> 16);
}

__device__ __forceinline__ void async16(void* lds, const void* g) {
  __builtin_amdgcn_global_load_lds((const __attribute__((address_space(1))) void*)g,
                                   (__attribute__((address_space(3))) void*)lds,
                                   16, 0, 0);
}

// x convert: float4 -> 4x bf16
__global__ void convert_x(const float* __restrict__ src,
                          unsigned short* __restrict__ dst, int n4) {
  int i = blockIdx.x * blockDim.x + threadIdx.x;
  if (i >= n4) return;
  const float4 f = ((const float4*)src)[i];
  ushort4 o;
  o.x = f2bf(f.x); o.y = f2bf(f.y); o.z = f2bf(f.z); o.w = f2bf(f.w);
  ((ushort4*)dst)[i] = o;
}

// three same-size weight converts in one launch; blockIdx.z selects
__global__ void convert_w(const float* __restrict__ s0, const float* __restrict__ s1,
                          const float* __restrict__ s2,
                          unsigned short* __restrict__ d0, unsigned short* __restrict__ d1,
                          unsigned short* __restrict__ d2, int n4) {
  const float* s = (blockIdx.z == 0) ? s0 : (blockIdx.z == 1) ? s1 : s2;
  unsigned short* d = (blockIdx.z == 0) ? d0 : (blockIdx.z == 1) ? d1 : d2;
  int i = blockIdx.x * blockDim.x + threadIdx.x;
  if (i >= n4) return;
  const float4 f = ((const float4*)s)[i];
  ushort4 o;
  o.x = f2bf(f.x); o.y = f2bf(f.y); o.z = f2bf(f.z); o.w = f2bf(f.w);
  ((ushort4*)d)[i] = o;
}

// C[m,n] = sum_k A[m,k]*B[n,k]  (A:[M,K], B:[N,K] bf16 row-major)
// GRID: blockIdx.x = M-tile, blockIdx.y = N-tile  (XCD L2 locality for A)
// MODE 0: store bf16 C*alpha.  gridDim.z==2 => z=1 uses B2/Cout2/alpha2 (QK fusion)
// MODE 1: store bf16 exp(C), atomicAdd per-row exp-sums into rowsum
// MODE 2: split-K over gridDim.z (kChunk each); atomicAdd fp32 C/rowsum[m] into Cout
template <int MODE>
__launch_bounds__(256)
__global__ void gemm_bt(const unsigned short* __restrict__ A,
                        const unsigned short* __restrict__ B,
                        void* __restrict__ Cout,
                        int M, int N, int K, float alpha,
                        float* __restrict__ rowsum, int kChunk,
                        const unsigned short* __restrict__ B2,
                        void* __restrict__ Cout2, float alpha2) {
  __shared__ __align__(16) unsigned short lA[128 * 32];
  __shared__ __align__(16) unsigned short lB[128 * 32];

  if (MODE == 0) {
    if (blockIdx.z == 1) { B = B2; Cout = Cout2; alpha = alpha2; }
  }
  const int kOff = (MODE == 2) ? blockIdx.z * kChunk : 0;

  const int t    = threadIdx.x;
  const int w    = t >> 6;
  const int l    = t & 63;
  const int quad = l >> 4;
  const int lr   = l & 15;
  const int m0   = blockIdx.x * 128;   // M on x: same-A blocks 64 ids apart -> same XCD
  const int n0   = blockIdx.y * 128;
  const int wm   = (w & 1) * 64;
  const int wn   = (w >> 1) * 64;

  f32x4 acc[4][4] = {};

  const int nk = kChunk >> 5;
  for (int kt = 0; kt < nk; ++kt) {
    const int k0 = kOff + (kt << 5);
    __syncthreads();
    // Stage A,B tiles: 512 x 16B chunks each; thread t takes chunks t, t+256.
    // LDS row-major [128][32] bf16; chunk c -> (row=c>>2, k=(c&3)*8);
    // lds byte offset c*16 = wave_base + lane*16 (global_load_lds constraint).
#pragma unroll
    for (int h = 0; h < 2; ++h) {
      int c   = t + (h << 8);
      int row = c >> 2;
      int kc  = (c & 3) << 3;
      async16(&lA[c << 3], A + (size_t)(m0 + row) * K + (k0 + kc));
      async16(&lB[c << 3], B + (size_t)(n0 + row) * K + (k0 + kc));
    }
    __syncthreads();

    bf16x8 af[4], bfr[4];
#pragma unroll
    for (int i = 0; i < 4; ++i) {
      af[i]  = *(const bf16x8*)&lA[(wm + i * 16 + lr) * 32 + quad * 8];
      bfr[i] = *(const bf16x8*)&lB[(wn + i * 16 + lr) * 32 + quad * 8];
    }
#pragma unroll
    for (int mi = 0; mi < 4; ++mi)
#pragma unroll
      for (int ni = 0; ni < 4; ++ni)
        acc[mi][ni] = __builtin_amdgcn_mfma_f32_16x16x32_bf16(af[mi], bfr[ni],
                                                              acc[mi][ni], 0, 0, 0);
  }

  // C/D layout (verified m89): col = lane&15, row = quad*4 + reg
  if (MODE == 0) {
    unsigned short* C = (unsigned short*)Cout;
#pragma unroll
    for (int mi = 0; mi < 4; ++mi)
#pragma unroll
      for (int r = 0; r < 4; ++r) {
        int m = m0 + wm + mi * 16 + quad * 4 + r;
#pragma unroll
        for (int ni = 0; ni < 4; ++ni) {
          int n = n0 + wn + ni * 16 + lr;
          C[(size_t)m * N + n] = f2bf(acc[mi][ni][r] * alpha);
        }
      }
  } else if (MODE == 1) {
    unsigned short* C = (unsigned short*)Cout;
#pragma unroll
    for (int mi = 0; mi < 4; ++mi)
#pragma unroll
      for (int r = 0; r < 4; ++r) {
        int m = m0 + wm + mi * 16 + quad * 4 + r;
        float s = 0.f;
#pragma unroll
        for (int ni = 0; ni < 4; ++ni) {
          int n = n0 + wn + ni * 16 + lr;
          float p = __expf(acc[mi][ni][r]);
          C[(size_t)m * N + n] = f2bf(p);
          s += p;
        }
#pragma unroll
        for (int off = 1; off < 16; off <<= 1) s += __shfl_xor(s, off, 64);
        if (lr == 0) atomicAdd(&rowsum[m], s);
      }
  } else {
    float* C = (float*)Cout;   // d_out fp32, zero-initialized; split-K partials
#pragma unroll
    for (int mi = 0; mi < 4; ++mi)
#pragma unroll
      for (int r = 0; r < 4; ++r) {
        int m = m0 + wm + mi * 16 + quad * 4 + r;
        float inv = 1.0f / rowsum[m];
#pragma unroll
        for (int ni = 0; ni < 4; ++ni) {
          int n = n0 + wn + ni * 16 + lr;
          atomicAdd(&C[(size_t)m * N + n], acc[mi][ni][r] * inv);
        }
      }
  }
}

extern "C" void kernel_launch(void* const* d_in, const int* in_sizes, int n_in,
                              void* d_out, int out_size, void* d_ws, size_t ws_size,
                              hipStream_t stream) {
  const float* x  = (const float*)d_in[0];
  const float* Wq = (const float*)d_in[1];
  const float* Wk = (const float*)d_in[2];
  const float* Wv = (const float*)d_in[3];

  char* ws = (char*)d_ws;
  unsigned short* xb     = (unsigned short*)(ws + 0);
  unsigned short* Qb     = (unsigned short*)(ws + 12582912);
  unsigned short* Kb     = (unsigned short*)(ws + 25165824);
  unsigned short* Vtb    = (unsigned short*)(ws + 37748736);
  unsigned short* wqb    = (unsigned short*)(ws + 50331648);
  unsigned short* wkb    = (unsigned short*)(ws + 51511296);
  unsigned short* wvb    = (unsigned short*)(ws + 52690944);
  float*          rowsum = (float*)(ws + 53870592);
  unsigned short* Pb     = (unsigned short*)(ws + 53903360);
  const size_t need = 53903360u + (size_t)SEQ * SEQ * 2u;
  if (ws_size < need) return;

  hipMemsetAsync(rowsum, 0, SEQ * sizeof(float), stream);
  hipMemsetAsync(d_out, 0, (size_t)out_size * sizeof(float), stream);

  convert_x<<<SEQ * DMODEL / 1024, 256, 0, stream>>>(x, xb, SEQ * DMODEL / 4);
  convert_w<<<dim3(DMODEL * DMODEL / 1024, 1, 3), 256, 0, stream>>>(
      Wq, Wk, Wv, wqb, wkb, wvb, DMODEL * DMODEL / 4);

  const float alpha_q = 0.03608439182435161f;  // 1/sqrt(768)
  dim3 blk(256);
  // NOTE: grid.x = M-tiles, grid.y = N-tiles (XCD swizzle)
  // Q=(x Wq^T)*alpha and K=x Wk^T fused (z selects)   [8192,768] each
  gemm_bt<0><<<dim3(SEQ / 128, DMODEL / 128, 2), blk, 0, stream>>>(
      xb, wqb, Qb, SEQ, DMODEL, DMODEL, alpha_q, nullptr, DMODEL,
      wkb, Kb, 1.0f);
  // Vt = Wv x^T   [768,8192]
  gemm_bt<0><<<dim3(DMODEL / 128, SEQ / 128, 1), blk, 0, stream>>>(
      wvb, xb, Vtb, DMODEL, SEQ, DMODEL, 1.0f, nullptr, DMODEL,
      nullptr, nullptr, 1.0f);
  // P' = exp(Q K^T) + rowsums   [8192,8192] bf16
  gemm_bt<1><<<dim3(SEQ / 128, SEQ / 128, 1), blk, 0, stream>>>(
      Qb, Kb, Pb, SEQ, SEQ, DMODEL, 1.0f, rowsum, DMODEL,
      nullptr, nullptr, 1.0f);
  // out += (P'_chunk V)/rowsum, split-K x4 -> fp32 d_out
  gemm_bt<2><<<dim3(SEQ / 128, DMODEL / 128, KSPLIT), blk, 0, stream>>>(
      Pb, Vtb, d_out, SEQ, DMODEL, SEQ, 1.0f, rowsum, SEQ / KSPLIT,
      nullptr, nullptr, 1.0f);
}

// Round 5
// 432.869 us; speedup vs baseline: 1.2454x; 1.0886x over previous
//
#include <hip/hip_runtime.h>
#include <stdint.h>

// Self-attention, SEQ=8192, D=768, single head.
//   K0a: x fp32->bf16; K0b: Wq/Wk/Wv fp32->bf16 (z-fused)
//   K1a: Q,K projections z-fused (MODE 0); K1b: Vt = Wv x^T (MODE 0)
//   K2 : P' = exp(Q K^T) bf16 + atomic row sums (MODE 1)
//   K3 : out += (P'_chunk V)/rowsum, split-K x4, fp32 atomicAdd (MODE 2)
// R3: x-fastest grids broke XCD L2 locality (FETCH 630MB) -> R4 M-on-x swizzle
//     fixed traffic (155MB = unique) but K3 only 225->193us: per-iter 502ns vs
//     m97's 307ns => barrier-drain (vmcnt(0)+s_barrier each BK=32 step) with
//     HBM-cold P' staging is ~50% of cycles.
// R5 change: BK=64 (half the drains, 32 MFMA/wave per drain, 32KB LDS) with
//     XOR-chunk swizzle in the staging map so ds_read_b128 stays bank-balanced
//     (plain [128][64] would idle half the banks: row*128B stride == 32 banks).

#define SEQ    8192
#define DMODEL 768
#define KSPLIT 4

typedef short bf16x8 __attribute__((ext_vector_type(8)));
typedef float f32x4  __attribute__((ext_vector_type(4)));

__device__ __forceinline__ unsigned short f2bf(float f) {
  union { float f; unsigned int u; } v; v.f = f;
  unsigned int u = v.u;
  u += 0x7FFFu + ((u >> 16) & 1u);   // round-to-nearest-even
  return (unsigned short)(u >> 16);
}

__device__ __forceinline__ void async16(void* lds, const void* g) {
  __builtin_amdgcn_global_load_lds((const __attribute__((address_space(1))) void*)g,
                                   (__attribute__((address_space(3))) void*)lds,
                                   16, 0, 0);
}

__global__ void convert_x(const float* __restrict__ src,
                          unsigned short* __restrict__ dst, int n4) {
  int i = blockIdx.x * blockDim.x + threadIdx.x;
  if (i >= n4) return;
  const float4 f = ((const float4*)src)[i];
  ushort4 o;
  o.x = f2bf(f.x); o.y = f2bf(f.y); o.z = f2bf(f.z); o.w = f2bf(f.w);
  ((ushort4*)dst)[i] = o;
}

__global__ void convert_w(const float* __restrict__ s0, const float* __restrict__ s1,
                          const float* __restrict__ s2,
                          unsigned short* __restrict__ d0, unsigned short* __restrict__ d1,
                          unsigned short* __restrict__ d2, int n4) {
  const float* s = (blockIdx.z == 0) ? s0 : (blockIdx.z == 1) ? s1 : s2;
  unsigned short* d = (blockIdx.z == 0) ? d0 : (blockIdx.z == 1) ? d1 : d2;
  int i = blockIdx.x * blockDim.x + threadIdx.x;
  if (i >= n4) return;
  const float4 f = ((const float4*)s)[i];
  ushort4 o;
  o.x = f2bf(f.x); o.y = f2bf(f.y); o.z = f2bf(f.z); o.w = f2bf(f.w);
  ((ushort4*)d)[i] = o;
}

// C[m,n] = sum_k A[m,k]*B[n,k]  (A:[M,K], B:[N,K] bf16 row-major)
// GRID: blockIdx.x = M-tile, blockIdx.y = N-tile (same-A blocks -> same XCD)
// BK=64 K-steps. LDS [128][64] with XOR-chunk swizzle:
//   LDS chunk (row, j) holds global k-chunk j^(row&7)  (chunks = 8 bf16 = 16B).
//   Staging keeps LDS addr = c*16 lane-linear (global_load_lds constraint);
//   readers index chunk ((h*4+quad) ^ (row&7)) -> all 32 banks balanced.
// MODE 0: bf16 C*alpha; z=1 uses B2/Cout2/alpha2 (QK fusion)
// MODE 1: bf16 exp(C) + atomicAdd per-row exp-sums into rowsum
// MODE 2: split-K over z (kChunk each); atomicAdd fp32 C/rowsum[m] into Cout
template <int MODE>
__launch_bounds__(256)
__global__ void gemm_bt(const unsigned short* __restrict__ A,
                        const unsigned short* __restrict__ B,
                        void* __restrict__ Cout,
                        int M, int N, int K, float alpha,
                        float* __restrict__ rowsum, int kChunk,
                        const unsigned short* __restrict__ B2,
                        void* __restrict__ Cout2, float alpha2) {
  __shared__ __align__(16) unsigned short lA[128 * 64];
  __shared__ __align__(16) unsigned short lB[128 * 64];

  if (MODE == 0) {
    if (blockIdx.z == 1) { B = B2; Cout = Cout2; alpha = alpha2; }
  }
  const int kOff = (MODE == 2) ? blockIdx.z * kChunk : 0;

  const int t    = threadIdx.x;
  const int w    = t >> 6;
  const int l    = t & 63;
  const int quad = l >> 4;
  const int lr   = l & 15;
  const int lr7  = lr & 7;
  const int m0   = blockIdx.x * 128;
  const int n0   = blockIdx.y * 128;
  const int wm   = (w & 1) * 64;
  const int wn   = (w >> 1) * 64;

  f32x4 acc[4][4] = {};

  const int nk = kChunk >> 6;
  for (int kt = 0; kt < nk; ++kt) {
    const int k0 = kOff + (kt << 6);
    __syncthreads();
    // Stage 128x64 tiles: 1024 x 16B chunks per tensor, 4 per thread.
    // chunk c -> row=c>>3, LDS col-chunk j=c&7 holds global chunk j^(row&7).
#pragma unroll
    for (int h = 0; h < 4; ++h) {
      int c   = t + (h << 8);
      int row = c >> 3;
      int swz = (c & 7) ^ (row & 7);
      async16(&lA[c << 3], A + (size_t)(m0 + row) * K + k0 + (swz << 3));
      async16(&lB[c << 3], B + (size_t)(n0 + row) * K + k0 + (swz << 3));
    }
    __syncthreads();

#pragma unroll
    for (int h = 0; h < 2; ++h) {
      bf16x8 af[4], bfr[4];
      const int g = (h << 2) | quad;        // desired global k-chunk
#pragma unroll
      for (int i = 0; i < 4; ++i) {
        const int rA = wm + i * 16 + lr;
        const int rB = wn + i * 16 + lr;
        af[i]  = *(const bf16x8*)&lA[rA * 64 + ((g ^ lr7) << 3)];
        bfr[i] = *(const bf16x8*)&lB[rB * 64 + ((g ^ lr7) << 3)];
      }
#pragma unroll
      for (int mi = 0; mi < 4; ++mi)
#pragma unroll
        for (int ni = 0; ni < 4; ++ni)
          acc[mi][ni] = __builtin_amdgcn_mfma_f32_16x16x32_bf16(af[mi], bfr[ni],
                                                                acc[mi][ni], 0, 0, 0);
    }
  }

  // C/D layout (verified m89): col = lane&15, row = quad*4 + reg
  if (MODE == 0) {
    unsigned short* C = (unsigned short*)Cout;
#pragma unroll
    for (int mi = 0; mi < 4; ++mi)
#pragma unroll
      for (int r = 0; r < 4; ++r) {
        int m = m0 + wm + mi * 16 + quad * 4 + r;
#pragma unroll
        for (int ni = 0; ni < 4; ++ni) {
          int n = n0 + wn + ni * 16 + lr;
          C[(size_t)m * N + n] = f2bf(acc[mi][ni][r] * alpha);
        }
      }
  } else if (MODE == 1) {
    unsigned short* C = (unsigned short*)Cout;
#pragma unroll
    for (int mi = 0; mi < 4; ++mi)
#pragma unroll
      for (int r = 0; r < 4; ++r) {
        int m = m0 + wm + mi * 16 + quad * 4 + r;
        float s = 0.f;
#pragma unroll
        for (int ni = 0; ni < 4; ++ni) {
          int n = n0 + wn + ni * 16 + lr;
          float p = __expf(acc[mi][ni][r]);
          C[(size_t)m * N + n] = f2bf(p);
          s += p;
        }
#pragma unroll
        for (int off = 1; off < 16; off <<= 1) s += __shfl_xor(s, off, 64);
        if (lr == 0) atomicAdd(&rowsum[m], s);
      }
  } else {
    float* C = (float*)Cout;   // d_out fp32, zero-initialized; split-K partials
#pragma unroll
    for (int mi = 0; mi < 4; ++mi)
#pragma unroll
      for (int r = 0; r < 4; ++r) {
        int m = m0 + wm + mi * 16 + quad * 4 + r;
        float inv = 1.0f / rowsum[m];
#pragma unroll
        for (int ni = 0; ni < 4; ++ni) {
          int n = n0 + wn + ni * 16 + lr;
          atomicAdd(&C[(size_t)m * N + n], acc[mi][ni][r] * inv);
        }
      }
  }
}

extern "C" void kernel_launch(void* const* d_in, const int* in_sizes, int n_in,
                              void* d_out, int out_size, void* d_ws, size_t ws_size,
                              hipStream_t stream) {
  const float* x  = (const float*)d_in[0];
  const float* Wq = (const float*)d_in[1];
  const float* Wk = (const float*)d_in[2];
  const float* Wv = (const float*)d_in[3];

  char* ws = (char*)d_ws;
  unsigned short* xb     = (unsigned short*)(ws + 0);
  unsigned short* Qb     = (unsigned short*)(ws + 12582912);
  unsigned short* Kb     = (unsigned short*)(ws + 25165824);
  unsigned short* Vtb    = (unsigned short*)(ws + 37748736);
  unsigned short* wqb    = (unsigned short*)(ws + 50331648);
  unsigned short* wkb    = (unsigned short*)(ws + 51511296);
  unsigned short* wvb    = (unsigned short*)(ws + 52690944);
  float*          rowsum = (float*)(ws + 53870592);
  unsigned short* Pb     = (unsigned short*)(ws + 53903360);
  const size_t need = 53903360u + (size_t)SEQ * SEQ * 2u;
  if (ws_size < need) return;

  hipMemsetAsync(rowsum, 0, SEQ * sizeof(float), stream);
  hipMemsetAsync(d_out, 0, (size_t)out_size * sizeof(float), stream);

  convert_x<<<SEQ * DMODEL / 1024, 256, 0, stream>>>(x, xb, SEQ * DMODEL / 4);
  convert_w<<<dim3(DMODEL * DMODEL / 1024, 1, 3), 256, 0, stream>>>(
      Wq, Wk, Wv, wqb, wkb, wvb, DMODEL * DMODEL / 4);

  const float alpha_q = 0.03608439182435161f;  // 1/sqrt(768)
  dim3 blk(256);
  // grid.x = M-tiles, grid.y = N-tiles (XCD L2 locality)
  gemm_bt<0><<<dim3(SEQ / 128, DMODEL / 128, 2), blk, 0, stream>>>(
      xb, wqb, Qb, SEQ, DMODEL, DMODEL, alpha_q, nullptr, DMODEL,
      wkb, Kb, 1.0f);
  gemm_bt<0><<<dim3(DMODEL / 128, SEQ / 128, 1), blk, 0, stream>>>(
      wvb, xb, Vtb, DMODEL, SEQ, DMODEL, 1.0f, nullptr, DMODEL,
      nullptr, nullptr, 1.0f);
  gemm_bt<1><<<dim3(SEQ / 128, SEQ / 128, 1), blk, 0, stream>>>(
      Qb, Kb, Pb, SEQ, SEQ, DMODEL, 1.0f, rowsum, DMODEL,
      nullptr, nullptr, 1.0f);
  gemm_bt<2><<<dim3(SEQ / 128, DMODEL / 128, KSPLIT), blk, 0, stream>>>(
      Pb, Vtb, d_out, SEQ, DMODEL, SEQ, 1.0f, rowsum, SEQ / KSPLIT,
      nullptr, nullptr, 1.0f);
}